// Round 5
// baseline (649.994 us; speedup 1.0000x reference)
//
#include <hip/hip_runtime.h>

// SimpleNonLocal: B=8, C=256, H=W=168, 3x3 grid of 56x56 patches, d=32.
// out = x + phi( Bc @ ((Bc^T Dn)/n) ) with Bc = Bn - mean(Bn), Bn = W_B x, Dn = W_D x.
// Restructured:
//   Bn[p,j,d], Dn[p,j,d]  (1x1 conv);  S[d,e] = sum_j Bn Dn;  T = S/n - mB mD
//   G[c,d] = sum_e W_phi[c,e] T[d,e];  h[c] = sum_d mB[d]/n G[c,d]
//   out[c,j] = x[c,j] + sum_d Bn[j,d] G[c,d] - h[c]
//
// R5: fuse kA+kB1 (Dn never touches HBM; S partials via LDS), kC z=2 channel
// split for occupancy (3.66 -> 7.3 waves/SIMD).

#define BB    8
#define CC    256
#define HH    168
#define WWs   168
#define HWs   28224       // 168*168
#define PH    56
#define NPOS  3136        // 56*56
#define NP    72          // 8 * 9 patches
#define DD    32
#define NPART 13          // S partials per patch (one per j-block)

// workspace layout (float offsets)
#define OFF_WBT 0                          // 256*32
#define OFF_WDT (OFF_WBT + 8192)           // 256*32
#define OFF_BN  (OFF_WDT + 8192)           // 72*32*3136 = 7225344
#define OFF_SP  (OFF_BN + 7225344)         // 72*13*1024 = 958464
#define OFF_MBP (OFF_SP + 958464)          // 72*13*32
#define OFF_MDP (OFF_MBP + 29952)          // 72*13*32
#define OFF_G   (OFF_MDP + 29952)          // 72*256*32
#define OFF_H   (OFF_G + 589824)           // 72*256

// ---- kernel 0: transpose W_B, W_D -> [c][d] so weight reads are wave-uniform.
__global__ void ktrans(const float* __restrict__ wb, const float* __restrict__ wd,
                       float* __restrict__ wbt, float* __restrict__ wdt) {
    const int c = threadIdx.x;
    #pragma unroll
    for (int d = 0; d < DD; ++d) {
        wbt[c * DD + d] = wb[d * CC + c];
        wdt[c * DD + d] = wd[d * CC + c];
    }
}

// ---- kernel AB (fused projection + S-partial). grid (13, 72), 256 thr.
// Phase 1: Bn/Dn in registers (8-deep x staging). Bn -> global; Dn stays on-chip.
// Phase 2: two 128-row LDS rounds, each thread owns a 2x2 (d,e) tile of S.
__global__ __launch_bounds__(256) void kAB(const float* __restrict__ x,
                                           const float* __restrict__ wbt,
                                           const float* __restrict__ wdt,
                                           float* __restrict__ bn,
                                           float* __restrict__ spart,
                                           float* __restrict__ mbp,
                                           float* __restrict__ mdp) {
    const int jb = blockIdx.x;      // 0..12
    const int p  = blockIdx.y;      // 0..71
    const int t  = threadIdx.x;
    const int j  = jb * 256 + t;
    const bool valid = j < NPOS;
    const int jc = valid ? j : (NPOS - 1);
    const int b  = p / 9;
    const int gy = (p % 9) / 3;
    const int gx = p % 3;
    const int iy = jc / PH;
    const int ix = jc % PH;
    const long base = (long)b * CC * HWs + (long)(gy * PH + iy) * WWs + (gx * PH + ix);

    float accB[DD], accD[DD];
    #pragma unroll
    for (int d = 0; d < DD; ++d) { accB[d] = 0.f; accD[d] = 0.f; }

    const float* xc = x + base;
    #pragma unroll 1
    for (int c0 = 0; c0 < CC; c0 += 8) {
        float xv[8];
        #pragma unroll
        for (int u = 0; u < 8; ++u) xv[u] = xc[(long)u * HWs];
        #pragma unroll
        for (int u = 0; u < 8; ++u) {
            const float* wbp = wbt + (c0 + u) * DD;
            const float* wdp = wdt + (c0 + u) * DD;
            #pragma unroll
            for (int d = 0; d < DD; ++d) {
                accB[d] = fmaf(xv[u], wbp[d], accB[d]);
                accD[d] = fmaf(xv[u], wdp[d], accD[d]);
            }
        }
        xc += 8L * HWs;
    }

    if (!valid) {
        #pragma unroll
        for (int d = 0; d < DD; ++d) { accB[d] = 0.f; accD[d] = 0.f; }
    } else {
        float* bp = bn + (long)p * DD * NPOS + j;
        #pragma unroll
        for (int d = 0; d < DD; ++d) bp[(long)d * NPOS] = accB[d];
    }

    // ---- phase 2: S partial over this block's 256 positions (invalid rows = 0).
    __shared__ float Bt[128][33];
    __shared__ float Dt[128][33];
    const int d2 = (t >> 4) << 1;   // 0,2,...,30
    const int e2 = (t & 15) << 1;
    float a00 = 0, a01 = 0, a10 = 0, a11 = 0;
    float mb0 = 0, mb1 = 0, md0 = 0, md1 = 0;

    #pragma unroll 1
    for (int r = 0; r < 2; ++r) {
        __syncthreads();
        if ((t >> 7) == r) {
            const int tr = t & 127;
            #pragma unroll
            for (int d = 0; d < DD; ++d) {
                Bt[tr][d] = accB[d];
                Dt[tr][d] = accD[d];
            }
        }
        __syncthreads();
        #pragma unroll 4
        for (int jj = 0; jj < 128; ++jj) {
            const float2 bv = *(const float2*)&Bt[jj][d2];
            const float2 dv = *(const float2*)&Dt[jj][e2];
            a00 = fmaf(bv.x, dv.x, a00);
            a01 = fmaf(bv.x, dv.y, a01);
            a10 = fmaf(bv.y, dv.x, a10);
            a11 = fmaf(bv.y, dv.y, a11);
            if (e2 == 0) { mb0 += bv.x; mb1 += bv.y; }
            if (d2 == 0) { md0 += dv.x; md1 += dv.y; }
        }
    }

    float* sp = spart + (long)(p * NPART + jb) * 1024;
    sp[(d2    ) * DD + e2    ] = a00;
    sp[(d2    ) * DD + e2 + 1] = a01;
    sp[(d2 + 1) * DD + e2    ] = a10;
    sp[(d2 + 1) * DD + e2 + 1] = a11;
    if (e2 == 0) { mbp[(p * NPART + jb) * DD + d2] = mb0; mbp[(p * NPART + jb) * DD + d2 + 1] = mb1; }
    if (d2 == 0) { mdp[(p * NPART + jb) * DD + e2] = md0; mdp[(p * NPART + jb) * DD + e2 + 1] = md1; }
}

// ---- kernel B2: reduce partials -> T -> G, h. grid (72), 256 thr.
__global__ __launch_bounds__(256) void kB2(const float* __restrict__ wphi,
                                           const float* __restrict__ spart,
                                           const float* __restrict__ mbp,
                                           const float* __restrict__ mdp,
                                           float* __restrict__ gout,
                                           float* __restrict__ hout) {
    const int p = blockIdx.x;
    const int t = threadIdx.x;
    __shared__ float Tm[DD][DD + 1];
    __shared__ float mbs[DD], mds[DD];

    if (t < DD) {
        float s1 = 0, s2 = 0;
        for (int q = 0; q < NPART; ++q) {
            s1 += mbp[(p * NPART + q) * DD + t];
            s2 += mdp[(p * NPART + q) * DD + t];
        }
        mbs[t] = s1; mds[t] = s2;
    }
    __syncthreads();

    const float invn = 1.0f / (float)NPOS;
    {
        float4 s = make_float4(0.f, 0.f, 0.f, 0.f);
        for (int q = 0; q < NPART; ++q) {
            const float4 v = *(const float4*)&spart[(long)(p * NPART + q) * 1024 + t * 4];
            s.x += v.x; s.y += v.y; s.z += v.z; s.w += v.w;
        }
        const int idx = t * 4;
        const int d = idx >> 5;
        const int e = idx & 31;
        const float mbd = mbs[d] * invn;
        Tm[d][e    ] = s.x * invn - mbd * (mds[e    ] * invn);
        Tm[d][e + 1] = s.y * invn - mbd * (mds[e + 1] * invn);
        Tm[d][e + 2] = s.z * invn - mbd * (mds[e + 2] * invn);
        Tm[d][e + 3] = s.w * invn - mbd * (mds[e + 3] * invn);
    }
    __syncthreads();

    const int c = t;
    float wp[DD];
    #pragma unroll
    for (int e = 0; e < DD; ++e) wp[e] = wphi[c * DD + e];
    float h = 0.f;
    float* gp = gout + ((long)p * CC + c) * DD;
    #pragma unroll 4
    for (int d = 0; d < DD; ++d) {
        float g = 0.f;
        #pragma unroll
        for (int e = 0; e < DD; ++e) g = fmaf(wp[e], Tm[d][e], g);
        gp[d] = g;
        h = fmaf(mbs[d] * invn, g, h);
    }
    hout[p * CC + c] = h;
}

// ---- kernel C: out = x + Bn*G^T - h. grid (13, 72, 2), 256 thr.
// z splits channels (128 each) -> 2x blocks -> 7.3 waves/SIMD for latency hiding.
__global__ __launch_bounds__(256) void kC(const float* __restrict__ x,
                                          const float* __restrict__ bn,
                                          const float* __restrict__ gbuf,
                                          const float* __restrict__ hbuf,
                                          float* __restrict__ out) {
    const int jb = blockIdx.x;
    const int p  = blockIdx.y;
    const int cbase = blockIdx.z * 128;
    const int t  = threadIdx.x;
    const int j  = jb * 256 + t;
    const bool valid = j < NPOS;
    const int jc = valid ? j : (NPOS - 1);
    const int b  = p / 9;
    const int gy = (p % 9) / 3;
    const int gx = p % 3;
    const int iy = jc / PH;
    const int ix = jc % PH;
    const long base = (long)b * CC * HWs + (long)(gy * PH + iy) * WWs + (gx * PH + ix)
                    + (long)cbase * HWs;

    float bnv[DD];
    const float* bp = bn + (long)p * DD * NPOS + jc;
    #pragma unroll
    for (int d = 0; d < DD; ++d) bnv[d] = bp[(long)d * NPOS];

    const float* gp = gbuf + (long)p * CC * DD + (long)cbase * DD;
    const float* hp = hbuf + p * CC + cbase;
    const float* xc = x + base;
    float* oc = out + base;
    #pragma unroll 1
    for (int c0 = 0; c0 < 128; c0 += 8) {
        float xv[8];
        #pragma unroll
        for (int u = 0; u < 8; ++u) xv[u] = xc[(long)u * HWs];
        #pragma unroll
        for (int u = 0; u < 8; ++u) {
            float acc = -hp[c0 + u];
            const float* g = gp + (c0 + u) * DD;
            #pragma unroll
            for (int d = 0; d < DD; ++d) acc = fmaf(bnv[d], g[d], acc);
            if (valid) oc[(long)u * HWs] = xv[u] + acc;
        }
        xc += 8L * HWs;
        oc += 8L * HWs;
    }
}

extern "C" void kernel_launch(void* const* d_in, const int* in_sizes, int n_in,
                              void* d_out, int out_size, void* d_ws, size_t ws_size,
                              hipStream_t stream) {
    const float* x    = (const float*)d_in[0];
    const float* wb   = (const float*)d_in[1];
    const float* wd   = (const float*)d_in[2];
    const float* wphi = (const float*)d_in[3];
    float* ws = (float*)d_ws;

    float* wbt = ws + OFF_WBT;
    float* wdt = ws + OFF_WDT;
    float* bnp = ws + OFF_BN;
    float* sp  = ws + OFF_SP;
    float* mbp = ws + OFF_MBP;
    float* mdp = ws + OFF_MDP;
    float* gb  = ws + OFF_G;
    float* hb  = ws + OFF_H;

    hipLaunchKernelGGL(ktrans, dim3(1), dim3(256), 0, stream, wb, wd, wbt, wdt);
    hipLaunchKernelGGL(kAB, dim3(13, 72), dim3(256), 0, stream, x, wbt, wdt, bnp, sp, mbp, mdp);
    hipLaunchKernelGGL(kB2, dim3(72), dim3(256), 0, stream, wphi, sp, mbp, mdp, gb, hb);
    hipLaunchKernelGGL(kC, dim3(13, 72, 2), dim3(256), 0, stream, x, bnp, gb, hb, (float*)d_out);
}

// Round 7
// 584.849 us; speedup vs baseline: 1.1114x; 1.1114x over previous
//
#include <hip/hip_runtime.h>

// SimpleNonLocal: B=8, C=256, H=W=168, 3x3 grid of 56x56 patches, d=32.
// out = x + phi( Bc @ ((Bc^T Dn)/n) ) with Bc = Bn - mean(Bn), Bn = W_B x, Dn = W_D x.
// Restructured:
//   Bn[p,j,d], Dn[p,j,d]  (1x1 conv);  S[d,e] = sum_j Bn Dn;  T = S/n - mB mD
//   G[c,d] = sum_e W_phi[c,e] T[d,e];  h[c] = sum_d mB[d]/n G[c,d]
//   out[c,j] = x[c,j] + sum_d Bn[j,d] G[c,d] - h[c]
//
// R6 (resubmitted R7 — broker timeout): R5's counters showed VGPR_Count
// (68 kAB / 32 kC) BELOW the working set (72+ / 40+ floats) -> compiler
// serialized everything; 8-deep staging never existed in the ISA. Fix:
// __launch_bounds__(256, 4) -> VGPR cap 128 (grid only supports 3.66
// blocks/CU anyway, so no occupancy loss). Also revert kC z-split.

#define BB    8
#define CC    256
#define HH    168
#define WWs   168
#define HWs   28224       // 168*168
#define PH    56
#define NPOS  3136        // 56*56
#define NP    72          // 8 * 9 patches
#define DD    32
#define NPART 13          // S partials per patch (one per j-block)

// workspace layout (float offsets)
#define OFF_WBT 0                          // 256*32
#define OFF_WDT (OFF_WBT + 8192)           // 256*32
#define OFF_BN  (OFF_WDT + 8192)           // 72*32*3136 = 7225344
#define OFF_SP  (OFF_BN + 7225344)         // 72*13*1024 = 958464
#define OFF_MBP (OFF_SP + 958464)          // 72*13*32
#define OFF_MDP (OFF_MBP + 29952)          // 72*13*32
#define OFF_G   (OFF_MDP + 29952)          // 72*256*32
#define OFF_H   (OFF_G + 589824)           // 72*256

// ---- kernel 0: transpose W_B, W_D -> [c][d] so weight reads are wave-uniform.
__global__ void ktrans(const float* __restrict__ wb, const float* __restrict__ wd,
                       float* __restrict__ wbt, float* __restrict__ wdt) {
    const int c = threadIdx.x;
    #pragma unroll
    for (int d = 0; d < DD; ++d) {
        wbt[c * DD + d] = wb[d * CC + c];
        wdt[c * DD + d] = wd[d * CC + c];
    }
}

// ---- kernel AB (fused projection + S-partial). grid (13, 72), 256 thr.
// Phase 1: Bn/Dn in registers (8-deep x staging). Bn -> global; Dn stays on-chip.
// Phase 2: two 128-row LDS rounds, each thread owns a 2x2 (d,e) tile of S.
__global__ __launch_bounds__(256, 4) void kAB(const float* __restrict__ x,
                                              const float* __restrict__ wbt,
                                              const float* __restrict__ wdt,
                                              float* __restrict__ bn,
                                              float* __restrict__ spart,
                                              float* __restrict__ mbp,
                                              float* __restrict__ mdp) {
    const int jb = blockIdx.x;      // 0..12
    const int p  = blockIdx.y;      // 0..71
    const int t  = threadIdx.x;
    const int j  = jb * 256 + t;
    const bool valid = j < NPOS;
    const int jc = valid ? j : (NPOS - 1);
    const int b  = p / 9;
    const int gy = (p % 9) / 3;
    const int gx = p % 3;
    const int iy = jc / PH;
    const int ix = jc % PH;
    const long base = (long)b * CC * HWs + (long)(gy * PH + iy) * WWs + (gx * PH + ix);

    float accB[DD], accD[DD];
    #pragma unroll
    for (int d = 0; d < DD; ++d) { accB[d] = 0.f; accD[d] = 0.f; }

    const float* xc = x + base;
    #pragma unroll 1
    for (int c0 = 0; c0 < CC; c0 += 8) {
        float xv[8];
        #pragma unroll
        for (int u = 0; u < 8; ++u) xv[u] = xc[(long)u * HWs];
        #pragma unroll
        for (int u = 0; u < 8; ++u) {
            const float* wbp = wbt + (c0 + u) * DD;
            const float* wdp = wdt + (c0 + u) * DD;
            #pragma unroll
            for (int d = 0; d < DD; ++d) {
                accB[d] = fmaf(xv[u], wbp[d], accB[d]);
                accD[d] = fmaf(xv[u], wdp[d], accD[d]);
            }
        }
        xc += 8L * HWs;
    }

    if (!valid) {
        #pragma unroll
        for (int d = 0; d < DD; ++d) { accB[d] = 0.f; accD[d] = 0.f; }
    } else {
        float* bp = bn + (long)p * DD * NPOS + j;
        #pragma unroll
        for (int d = 0; d < DD; ++d) bp[(long)d * NPOS] = accB[d];
    }

    // ---- phase 2: S partial over this block's 256 positions (invalid rows = 0).
    __shared__ float Bt[128][33];
    __shared__ float Dt[128][33];
    const int d2 = (t >> 4) << 1;   // 0,2,...,30
    const int e2 = (t & 15) << 1;
    float a00 = 0, a01 = 0, a10 = 0, a11 = 0;
    float mb0 = 0, mb1 = 0, md0 = 0, md1 = 0;

    #pragma unroll 1
    for (int r = 0; r < 2; ++r) {
        __syncthreads();
        if ((t >> 7) == r) {
            const int tr = t & 127;
            #pragma unroll
            for (int d = 0; d < DD; ++d) {
                Bt[tr][d] = accB[d];
                Dt[tr][d] = accD[d];
            }
        }
        __syncthreads();
        #pragma unroll 4
        for (int jj = 0; jj < 128; ++jj) {
            const float2 bv = *(const float2*)&Bt[jj][d2];
            const float2 dv = *(const float2*)&Dt[jj][e2];
            a00 = fmaf(bv.x, dv.x, a00);
            a01 = fmaf(bv.x, dv.y, a01);
            a10 = fmaf(bv.y, dv.x, a10);
            a11 = fmaf(bv.y, dv.y, a11);
            if (e2 == 0) { mb0 += bv.x; mb1 += bv.y; }
            if (d2 == 0) { md0 += dv.x; md1 += dv.y; }
        }
    }

    float* sp = spart + (long)(p * NPART + jb) * 1024;
    sp[(d2    ) * DD + e2    ] = a00;
    sp[(d2    ) * DD + e2 + 1] = a01;
    sp[(d2 + 1) * DD + e2    ] = a10;
    sp[(d2 + 1) * DD + e2 + 1] = a11;
    if (e2 == 0) { mbp[(p * NPART + jb) * DD + d2] = mb0; mbp[(p * NPART + jb) * DD + d2 + 1] = mb1; }
    if (d2 == 0) { mdp[(p * NPART + jb) * DD + e2] = md0; mdp[(p * NPART + jb) * DD + e2 + 1] = md1; }
}

// ---- kernel B2: reduce partials -> T -> G, h. grid (72), 256 thr.
__global__ __launch_bounds__(256) void kB2(const float* __restrict__ wphi,
                                           const float* __restrict__ spart,
                                           const float* __restrict__ mbp,
                                           const float* __restrict__ mdp,
                                           float* __restrict__ gout,
                                           float* __restrict__ hout) {
    const int p = blockIdx.x;
    const int t = threadIdx.x;
    __shared__ float Tm[DD][DD + 1];
    __shared__ float mbs[DD], mds[DD];

    if (t < DD) {
        float s1 = 0, s2 = 0;
        for (int q = 0; q < NPART; ++q) {
            s1 += mbp[(p * NPART + q) * DD + t];
            s2 += mdp[(p * NPART + q) * DD + t];
        }
        mbs[t] = s1; mds[t] = s2;
    }
    __syncthreads();

    const float invn = 1.0f / (float)NPOS;
    {
        float4 s = make_float4(0.f, 0.f, 0.f, 0.f);
        for (int q = 0; q < NPART; ++q) {
            const float4 v = *(const float4*)&spart[(long)(p * NPART + q) * 1024 + t * 4];
            s.x += v.x; s.y += v.y; s.z += v.z; s.w += v.w;
        }
        const int idx = t * 4;
        const int d = idx >> 5;
        const int e = idx & 31;
        const float mbd = mbs[d] * invn;
        Tm[d][e    ] = s.x * invn - mbd * (mds[e    ] * invn);
        Tm[d][e + 1] = s.y * invn - mbd * (mds[e + 1] * invn);
        Tm[d][e + 2] = s.z * invn - mbd * (mds[e + 2] * invn);
        Tm[d][e + 3] = s.w * invn - mbd * (mds[e + 3] * invn);
    }
    __syncthreads();

    const int c = t;
    float wp[DD];
    #pragma unroll
    for (int e = 0; e < DD; ++e) wp[e] = wphi[c * DD + e];
    float h = 0.f;
    float* gp = gout + ((long)p * CC + c) * DD;
    #pragma unroll 4
    for (int d = 0; d < DD; ++d) {
        float g = 0.f;
        #pragma unroll
        for (int e = 0; e < DD; ++e) g = fmaf(wp[e], Tm[d][e], g);
        gp[d] = g;
        h = fmaf(mbs[d] * invn, g, h);
    }
    hout[p * CC + c] = h;
}

// ---- kernel C: out = x + Bn*G^T - h. grid (13, 72), 256 thr.
// bnv resident in 32 VGPRs + 8-deep x staging (needs ~80 regs -> launch_bounds
// relaxed). G/h rows block-uniform (s_load); x/out coalesced.
__global__ __launch_bounds__(256, 4) void kC(const float* __restrict__ x,
                                             const float* __restrict__ bn,
                                             const float* __restrict__ gbuf,
                                             const float* __restrict__ hbuf,
                                             float* __restrict__ out) {
    const int jb = blockIdx.x;
    const int p  = blockIdx.y;
    const int t  = threadIdx.x;
    const int j  = jb * 256 + t;
    const bool valid = j < NPOS;
    const int jc = valid ? j : (NPOS - 1);
    const int b  = p / 9;
    const int gy = (p % 9) / 3;
    const int gx = p % 3;
    const int iy = jc / PH;
    const int ix = jc % PH;
    const long base = (long)b * CC * HWs + (long)(gy * PH + iy) * WWs + (gx * PH + ix);

    float bnv[DD];
    const float* bp = bn + (long)p * DD * NPOS + jc;
    #pragma unroll
    for (int d = 0; d < DD; ++d) bnv[d] = bp[(long)d * NPOS];

    const float* gp = gbuf + (long)p * CC * DD;
    const float* hp = hbuf + p * CC;
    const float* xc = x + base;
    float* oc = out + base;
    #pragma unroll 1
    for (int c0 = 0; c0 < CC; c0 += 8) {
        float xv[8];
        #pragma unroll
        for (int u = 0; u < 8; ++u) xv[u] = xc[(long)u * HWs];
        #pragma unroll
        for (int u = 0; u < 8; ++u) {
            float acc = -hp[c0 + u];
            const float* g = gp + (c0 + u) * DD;
            #pragma unroll
            for (int d = 0; d < DD; ++d) acc = fmaf(bnv[d], g[d], acc);
            if (valid) oc[(long)u * HWs] = xv[u] + acc;
        }
        xc += 8L * HWs;
        oc += 8L * HWs;
    }
}

extern "C" void kernel_launch(void* const* d_in, const int* in_sizes, int n_in,
                              void* d_out, int out_size, void* d_ws, size_t ws_size,
                              hipStream_t stream) {
    const float* x    = (const float*)d_in[0];
    const float* wb   = (const float*)d_in[1];
    const float* wd   = (const float*)d_in[2];
    const float* wphi = (const float*)d_in[3];
    float* ws = (float*)d_ws;

    float* wbt = ws + OFF_WBT;
    float* wdt = ws + OFF_WDT;
    float* bnp = ws + OFF_BN;
    float* sp  = ws + OFF_SP;
    float* mbp = ws + OFF_MBP;
    float* mdp = ws + OFF_MDP;
    float* gb  = ws + OFF_G;
    float* hb  = ws + OFF_H;

    hipLaunchKernelGGL(ktrans, dim3(1), dim3(256), 0, stream, wb, wd, wbt, wdt);
    hipLaunchKernelGGL(kAB, dim3(13, 72), dim3(256), 0, stream, x, wbt, wdt, bnp, sp, mbp, mdp);
    hipLaunchKernelGGL(kB2, dim3(72), dim3(256), 0, stream, wphi, sp, mbp, mdp, gb, hb);
    hipLaunchKernelGGL(kC, dim3(13, 72), dim3(256), 0, stream, x, bnp, gb, hb, (float*)d_out);
}